// Round 4
// baseline (421.969 us; speedup 1.0000x reference)
//
#include <hip/hip_runtime.h>

// ---------------- problem constants ----------------
// Inputs float32; d_out float32 (reference output dtype). Concat: fc, conv, flat, rnn.
#define FEAT 11664           // 16 * 27 * 27
#define OFF_FC   0u
#define OFF_CONV 4096u
#define OFF_FLAT 23891968u   // 4096 + 2048*11664
#define OFF_RNN  47779840u   // OFF_FLAT + 2048*11664
#define PADF 732             // 729 padded to multiple of 4 for float4 dots

// ---------------- K1: conv + bias -> out_conv ; relu -> out_flat ----------------
// grid = 2048 frames (b*64+t), block = 128 = (kg 0..3)*(r 0..31, active r<27).
__global__ __launch_bounds__(128) void k_conv(const float* __restrict__ x,
                                              const float* __restrict__ cw,
                                              const float* __restrict__ cb,
                                              float* __restrict__ out)
{
    __shared__ __align__(16) float xs[2 * 32 * 36];   // padded rows (36)
    __shared__ __align__(16) float wls[72 * 16];      // [ch*36 + i*6 + j][k]
    __shared__ float bls[16];
    const int tid = threadIdx.x;
    const int frame = blockIdx.x;

    const float4* xg = (const float4*)(x + (size_t)frame * 2048);
    for (int c0 = tid; c0 < 512; c0 += 128) {
        float4 v = xg[c0];
        int e0 = c0 * 4;
        int ch = e0 >> 10, rem = e0 & 1023, row = rem >> 5, col = rem & 31;
        float* dst = &xs[ch * 1152 + row * 36 + col];
        dst[0] = v.x; dst[1] = v.y; dst[2] = v.z; dst[3] = v.w;
    }
    for (int idx = tid; idx < 1152; idx += 128) {
        int k = idx / 72;
        int rem = idx - k * 72;
        wls[rem * 16 + k] = cw[idx];
    }
    if (tid < 16) bls[tid] = cb[tid];
    __syncthreads();

    const int kg = tid >> 5;
    const int r  = tid & 31;
    if (r < 27) {
        float acc[4][27];
        #pragma unroll
        for (int kk = 0; kk < 4; ++kk)
            #pragma unroll
            for (int c = 0; c < 27; ++c) acc[kk][c] = 0.f;

        for (int ch = 0; ch < 2; ++ch) {
            for (int i = 0; i < 6; ++i) {
                const float* rowp = &xs[ch * 1152 + (r + i) * 36];
                float xr[32];
                #pragma unroll
                for (int m = 0; m < 8; ++m) {
                    float4 v = ((const float4*)rowp)[m];
                    xr[4*m+0] = v.x; xr[4*m+1] = v.y; xr[4*m+2] = v.z; xr[4*m+3] = v.w;
                }
                float4 wj[6];
                #pragma unroll
                for (int j = 0; j < 6; ++j)
                    wj[j] = *(const float4*)&wls[(ch * 36 + i * 6 + j) * 16 + kg * 4];
                #pragma unroll
                for (int j = 0; j < 6; ++j) {
                    #pragma unroll
                    for (int c = 0; c < 27; ++c) {
                        float xv = xr[c + j];
                        acc[0][c] = fmaf(xv, wj[j].x, acc[0][c]);
                        acc[1][c] = fmaf(xv, wj[j].y, acc[1][c]);
                        acc[2][c] = fmaf(xv, wj[j].z, acc[2][c]);
                        acc[3][c] = fmaf(xv, wj[j].w, acc[3][c]);
                    }
                }
            }
        }
        #pragma unroll
        for (int kk = 0; kk < 4; ++kk) {
            int k = kg * 4 + kk;
            float bv = bls[k];
            size_t base = (size_t)frame * FEAT + (size_t)k * 729 + (size_t)r * 27;
            float* oc = out + OFF_CONV + base;
            float* of = out + OFF_FLAT + base;
            #pragma unroll
            for (int c = 0; c < 27; ++c) {
                float v = acc[kk][c] + bv;
                oc[c] = v;
                of[c] = v > 0.f ? v : 0.f;
            }
        }
    }
}

// ---------------- K2: adaptive scan + x@w_ih^T projection (plain VALU) ----------------
// grid = 32 b * 16 f-blocks (729 feats each); block = 256 threads.
// Per t-tile of 16: threads 0..242 run the adapt chain (3 feats each, fp32 state,
// sequential over t) writing adapted fp32 into LDS; then thread (t=tid>>4,u=tid&15)
// computes C[t][u] as a 729-length fp32 dot (float4 LDS reads, zero-padded tail).
// Per-block partial sums go race-free to ws: partial[fb][b][t][u].
__global__ __launch_bounds__(256) void k_adapt_proj(const float* __restrict__ flat,
                                                    const float* __restrict__ w_ih,
                                                    float* __restrict__ partial)
{
    __shared__ __align__(16) float A32[16 * PADF];   // [t_local][f]
    __shared__ __align__(16) float Bw32[16 * PADF];  // [u][f]
    const int tid = threadIdx.x;
    const int b  = blockIdx.x >> 4;
    const int fb = blockIdx.x & 15;
    const int fbase = fb * 729;

    // stage w_ih slice (fp32); zero pad cols 729..731 of both arrays
    for (int n = 0; n < 16; ++n) {
        const float* src = w_ih + (size_t)n * FEAT + fbase;
        for (int f = tid; f < 729; f += 256) Bw32[n * PADF + f] = src[f];
    }
    if (tid < 48) {
        int n = tid / 3, c = 729 + (tid % 3);
        A32[n * PADF + c]  = 0.f;
        Bw32[n * PADF + c] = 0.f;
    }
    __syncthreads();

    float ad0 = 0.f, ad1 = 0.f, ad2 = 0.f;  // adapt state for this thread's 3 feats
    const int tl_ = tid >> 4, u_ = tid & 15;

    for (int tt = 0; tt < 4; ++tt) {
        if (tid < 243) {
            const float* src = flat + (size_t)(b * 64 + tt * 16) * FEAT + fbase + tid * 3;
            float* arow = &A32[tid * 3];
            #pragma unroll
            for (int tl = 0; tl < 16; ++tl) {
                const float* p = src + (size_t)tl * FEAT;
                float f0 = p[0], f1 = p[1], f2 = p[2];
                float o0 = fmaxf(f0 - ad0, 0.f); ad0 = (ad0 + 0.1f * o0) * 0.9f;
                float o1 = fmaxf(f1 - ad1, 0.f); ad1 = (ad1 + 0.1f * o1) * 0.9f;
                float o2 = fmaxf(f2 - ad2, 0.f); ad2 = (ad2 + 0.1f * o2) * 0.9f;
                float* dst = arow + tl * PADF;
                dst[0] = o0; dst[1] = o1; dst[2] = o2;
            }
        }
        __syncthreads();

        {
            const float4* arow = (const float4*)&A32[tl_ * PADF];
            const float4* brow = (const float4*)&Bw32[u_ * PADF];
            float s0 = 0.f, s1 = 0.f, s2 = 0.f, s3 = 0.f;
            for (int f4 = 0; f4 < PADF / 4; ++f4) {    // 183 iters, pads are zero
                float4 a = arow[f4], w = brow[f4];
                s0 = fmaf(a.x, w.x, s0);
                s1 = fmaf(a.y, w.y, s1);
                s2 = fmaf(a.z, w.z, s2);
                s3 = fmaf(a.w, w.w, s3);
            }
            float s = (s0 + s1) + (s2 + s3);
            partial[(size_t)(((fb * 32 + b) * 64 + tt * 16 + tl_) * 16) + u_] = s;
        }
        __syncthreads();
    }
}

// ---------------- K3: sum partials + SimpleRNN (with adaptation) + FC ----------------
// grid = 8 blocks * 64 threads (1 wave): lanes = (bl 0..3, u 0..15), b = blk*4+bl.
__global__ __launch_bounds__(64) void k_rnn(const float* __restrict__ partial,
                                            const float* __restrict__ w_hh,
                                            const float* __restrict__ b_ih,
                                            const float* __restrict__ b_hh,
                                            const float* __restrict__ fc_w,
                                            const float* __restrict__ fc_b,
                                            float* __restrict__ out)
{
    __shared__ __align__(16) float preL[4096];   // [bl][t][u]
    __shared__ float hL[64];                     // [bl][u]
    const int l = threadIdx.x;
    const int bl = l >> 4, u = l & 15;
    const int b = blockIdx.x * 4 + bl;

    // pre[b][t][u] = sum over the 16 feature-block partials (deterministic order)
    const float4* p4 = (const float4*)partial;   // 8192 float4 per fb slab
    float4* pl4 = (float4*)preL;
    for (int c = l; c < 1024; c += 64) {
        float4 s = {0.f, 0.f, 0.f, 0.f};
        for (int fb = 0; fb < 16; ++fb) {
            float4 v = p4[(size_t)fb * 8192 + blockIdx.x * 1024 + c];
            s.x += v.x; s.y += v.y; s.z += v.z; s.w += v.w;
        }
        pl4[c] = s;
    }

    float wv[16];
    #pragma unroll
    for (int mm = 0; mm < 4; ++mm) {
        float4 t4 = *(const float4*)(w_hh + u * 16 + mm * 4);
        wv[4*mm+0] = t4.x; wv[4*mm+1] = t4.y; wv[4*mm+2] = t4.z; wv[4*mm+3] = t4.w;
    }
    const float bsum = b_ih[u] + b_hh[u];
    float frow[16]; float fcb = 0.f;
    if (u < 2) {
        #pragma unroll
        for (int mm = 0; mm < 4; ++mm) {
            float4 t4 = *(const float4*)(fc_w + u * 16 + mm * 4);
            frow[4*mm+0] = t4.x; frow[4*mm+1] = t4.y; frow[4*mm+2] = t4.z; frow[4*mm+3] = t4.w;
        }
        fcb = fc_b[u];
    }
    hL[l] = 0.f;
    float ad = 0.f;
    __syncthreads();

    for (int t = 0; t < 64; ++t) {
        float hv[16];
        #pragma unroll
        for (int mm = 0; mm < 4; ++mm) {
            float4 h4 = *(const float4*)&hL[bl * 16 + mm * 4];
            hv[4*mm+0] = h4.x; hv[4*mm+1] = h4.y; hv[4*mm+2] = h4.z; hv[4*mm+3] = h4.w;
        }
        if (t > 0 && u < 2) {   // FC for t-1 from h_{t-1}
            float fcv = fcb;
            #pragma unroll
            for (int v2 = 0; v2 < 16; ++v2) fcv = fmaf(hv[v2], frow[v2], fcv);
            out[OFF_FC + (size_t)(b * 64 + (t - 1)) * 2 + u] = fcv;
        }
        float dot = 0.f;
        #pragma unroll
        for (int v2 = 0; v2 < 16; ++v2) dot = fmaf(hv[v2], wv[v2], dot);
        float v = preL[(bl * 64 + t) * 16 + u] + bsum + dot;
        float a = v - ad; a = a > 0.f ? a : 0.f;   // a = relu(pre - adapt); h = relu(a) = a
        ad = (ad + 0.4f * a) * 0.9f;
        out[OFF_RNN + (size_t)(b * 64 + t) * 16 + u] = a;
        __syncthreads();
        hL[l] = a;
        __syncthreads();
    }
    {   // FC for t = 63
        float hv[16];
        #pragma unroll
        for (int mm = 0; mm < 4; ++mm) {
            float4 h4 = *(const float4*)&hL[bl * 16 + mm * 4];
            hv[4*mm+0] = h4.x; hv[4*mm+1] = h4.y; hv[4*mm+2] = h4.z; hv[4*mm+3] = h4.w;
        }
        if (u < 2) {
            float fcv = fcb;
            #pragma unroll
            for (int v2 = 0; v2 < 16; ++v2) fcv = fmaf(hv[v2], frow[v2], fcv);
            out[OFF_FC + (size_t)(b * 64 + 63) * 2 + u] = fcv;
        }
    }
}

extern "C" void kernel_launch(void* const* d_in, const int* in_sizes, int n_in,
                              void* d_out, int out_size, void* d_ws, size_t ws_size,
                              hipStream_t stream)
{
    const float* x    = (const float*)d_in[0];
    const float* cw   = (const float*)d_in[1];
    const float* cb   = (const float*)d_in[2];
    const float* w_ih = (const float*)d_in[3];
    const float* w_hh = (const float*)d_in[4];
    const float* b_ih = (const float*)d_in[5];
    const float* b_hh = (const float*)d_in[6];
    const float* fc_w = (const float*)d_in[7];
    const float* fc_b = (const float*)d_in[8];
    float* out = (float*)d_out;
    float* partial = (float*)d_ws;   // 16 fb * 32 b * 64 t * 16 u fp32 = 2 MB

    k_conv<<<2048, 128, 0, stream>>>(x, cw, cb, out);
    k_adapt_proj<<<512, 256, 0, stream>>>(out + OFF_FLAT, w_ih, partial);
    k_rnn<<<8, 64, 0, stream>>>(partial, w_hh, b_ih, b_hh, fc_w, fc_b, out);
}

// Round 5
// 345.380 us; speedup vs baseline: 1.2218x; 1.2218x over previous
//
#include <hip/hip_runtime.h>

// ---------------- problem constants ----------------
// Inputs float32; d_out float32. Concat: fc, conv, flat, rnn.
#define FEAT 11664           // 16 * 27 * 27
#define OFF_FC   0u
#define OFF_CONV 4096u
#define OFF_FLAT 23891968u   // 4096 + 2048*11664
#define OFF_RNN  47779840u   // OFF_FLAT + 2048*11664

static __device__ __forceinline__ unsigned short f2bf(float f) {
    unsigned int u = __float_as_uint(f);
    u += 0x7FFFu + ((u >> 16) & 1u);       // round-to-nearest-even
    return (unsigned short)(u >> 16);
}

// ---------------- K1: conv + bias -> out_conv ; relu -> out_flat ----------------
// grid = 2048 frames (b*64+t), block = 128 = (kg 0..3)*(r 0..31, active r<27).
// Epilogue stages each kk-chunk (4 k x 729) in LDS (aliased over dead xs/wls)
// and writes coalesced contiguous dword stores (fixes 1.54x write amplification).
__global__ __launch_bounds__(128) void k_conv(const float* __restrict__ x,
                                              const float* __restrict__ cw,
                                              const float* __restrict__ cb,
                                              float* __restrict__ out)
{
    __shared__ __align__(16) float smem[3456];  // xs(2304) + wls(1152); reused as ot(2916)
    __shared__ float bls[16];
    float* xs  = smem;          // [ch(2)][row(32)][col(36 padded)]
    float* wls = smem + 2304;   // [ch*36 + i*6 + j][k(16)]
    float* ot  = smem;          // [kg(4)][r(27)][c(27)] epilogue tile (after barrier)
    const int tid = threadIdx.x;
    const int frame = blockIdx.x;

    const float4* xg = (const float4*)(x + (size_t)frame * 2048);
    for (int c0 = tid; c0 < 512; c0 += 128) {
        float4 v = xg[c0];
        int e0 = c0 * 4;
        int ch = e0 >> 10, rem = e0 & 1023, row = rem >> 5, col = rem & 31;
        float* dst = &xs[ch * 1152 + row * 36 + col];
        dst[0] = v.x; dst[1] = v.y; dst[2] = v.z; dst[3] = v.w;
    }
    for (int idx = tid; idx < 1152; idx += 128) {
        int k = idx / 72;
        int rem = idx - k * 72;
        wls[rem * 16 + k] = cw[idx];
    }
    if (tid < 16) bls[tid] = cb[tid];
    __syncthreads();

    const int kg = tid >> 5;
    const int r  = tid & 31;
    float acc[4][27];
    if (r < 27) {
        #pragma unroll
        for (int kk = 0; kk < 4; ++kk)
            #pragma unroll
            for (int c = 0; c < 27; ++c) acc[kk][c] = 0.f;

        for (int ch = 0; ch < 2; ++ch) {
            for (int i = 0; i < 6; ++i) {
                const float* rowp = &xs[ch * 1152 + (r + i) * 36];
                float xr[32];
                #pragma unroll
                for (int m = 0; m < 8; ++m) {
                    float4 v = ((const float4*)rowp)[m];
                    xr[4*m+0] = v.x; xr[4*m+1] = v.y; xr[4*m+2] = v.z; xr[4*m+3] = v.w;
                }
                float4 wj[6];
                #pragma unroll
                for (int j = 0; j < 6; ++j)
                    wj[j] = *(const float4*)&wls[(ch * 36 + i * 6 + j) * 16 + kg * 4];
                #pragma unroll
                for (int j = 0; j < 6; ++j) {
                    #pragma unroll
                    for (int c = 0; c < 27; ++c) {
                        float xv = xr[c + j];
                        acc[0][c] = fmaf(xv, wj[j].x, acc[0][c]);
                        acc[1][c] = fmaf(xv, wj[j].y, acc[1][c]);
                        acc[2][c] = fmaf(xv, wj[j].z, acc[2][c]);
                        acc[3][c] = fmaf(xv, wj[j].w, acc[3][c]);
                    }
                }
            }
        }
    }

    // epilogue: 4 chunks; chunk kk covers k = {kk, kk+4, kk+8, kk+12} (one per kg)
    for (int kk = 0; kk < 4; ++kk) {
        __syncthreads();   // kk=0: protects xs/wls reads; else: previous chunk's reads
        if (r < 27) {
            float bv = bls[kg * 4 + kk];
            float* dst = &ot[kg * 729 + r * 27];
            #pragma unroll
            for (int c = 0; c < 27; ++c) dst[c] = acc[kk][c] + bv;
        }
        __syncthreads();
        #pragma unroll
        for (int kg2 = 0; kg2 < 4; ++kg2) {
            const float* src = &ot[kg2 * 729];
            size_t gbase = (size_t)frame * FEAT + (size_t)(kg2 * 4 + kk) * 729;
            for (int e = tid; e < 729; e += 128) {
                float v = src[e];
                out[OFF_CONV + gbase + e] = v;
                out[OFF_FLAT + gbase + e] = v > 0.f ? v : 0.f;
            }
        }
    }
}

// ---------------- K2: fused adaptive scan + x@w_ih^T projection (MFMA) ----------------
// grid = 32 b * 16 f-blocks (729 feats each); block = 256 threads (4 waves).
// Per t-tile of 16: threads 0..242 preload 48 operands (address-static), run the
// adapt chain in regs, write bf16 adapted into LDS A [t][f]; 23 K-steps of
// mfma_f32_16x16x32_bf16 split over 4 waves; deterministic partial[fb] writes.
typedef short bf16x8 __attribute__((ext_vector_type(8)));
typedef float f32x4  __attribute__((ext_vector_type(4)));

__global__ __launch_bounds__(256) void k_adapt_proj(const float* __restrict__ flat,
                                                    const float* __restrict__ w_ih,
                                                    float* __restrict__ partial)
{
    __shared__ __align__(16) unsigned short A[16 * 744];    // [t_local][f], pad->744
    __shared__ __align__(16) unsigned short Bw[16 * 744];   // [u][f] (= B^T rows)
    __shared__ __align__(16) float accscr[4 * 64 * 4];
    const int tid = threadIdx.x;
    const int b  = blockIdx.x >> 4;
    const int fb = blockIdx.x & 15;
    const int fbase = fb * 729;

    for (int n = 0; n < 16; ++n) {
        const float* src = w_ih + (size_t)n * FEAT + fbase;
        for (int f = tid; f < 729; f += 256) Bw[n * 744 + f] = f2bf(src[f]);
    }
    if (tid < 240) {
        int n = tid / 15, c = 729 + (tid % 15);
        A[n * 744 + c]  = 0;
        Bw[n * 744 + c] = 0;
    }
    __syncthreads();

    float ad0 = 0.f, ad1 = 0.f, ad2 = 0.f;  // adapt state for this thread's 3 feats
    const int w = tid >> 6, l = tid & 63;
    const int m = l & 15, q = l >> 4;       // MFMA lane decomposition

    for (int tt = 0; tt < 4; ++tt) {
        if (tid < 243) {
            const float* src = flat + (size_t)(b * 64 + tt * 16) * FEAT + fbase + tid * 3;
            float v0[16], v1[16], v2[16];
            #pragma unroll
            for (int tl = 0; tl < 16; ++tl) {   // independent loads: one round-trip
                const float* p = src + (size_t)tl * FEAT;
                v0[tl] = p[0]; v1[tl] = p[1]; v2[tl] = p[2];
            }
            unsigned short* arow = &A[tid * 3];
            #pragma unroll
            for (int tl = 0; tl < 16; ++tl) {
                float o0 = fmaxf(v0[tl] - ad0, 0.f); ad0 = (ad0 + 0.1f * o0) * 0.9f;
                float o1 = fmaxf(v1[tl] - ad1, 0.f); ad1 = (ad1 + 0.1f * o1) * 0.9f;
                float o2 = fmaxf(v2[tl] - ad2, 0.f); ad2 = (ad2 + 0.1f * o2) * 0.9f;
                unsigned short* dst = arow + tl * 744;
                dst[0] = f2bf(o0); dst[1] = f2bf(o1); dst[2] = f2bf(o2);
            }
        }
        __syncthreads();

        f32x4 acc = {0.f, 0.f, 0.f, 0.f};
        for (int s = w; s < 23; s += 4) {   // 736 = 23*32 K-steps, zero-padded tail
            int k0 = s * 32;
            bf16x8 av = *(const bf16x8*)&A [m * 744 + k0 + q * 8];
            bf16x8 bv = *(const bf16x8*)&Bw[m * 744 + k0 + q * 8];
            acc = __builtin_amdgcn_mfma_f32_16x16x32_bf16(av, bv, acc, 0, 0, 0);
        }
        *(f32x4*)&accscr[(w * 64 + l) * 4] = acc;
        __syncthreads();
        {
            int ll = tid >> 2, rg = tid & 3;
            float s = accscr[(0 * 64 + ll) * 4 + rg] + accscr[(1 * 64 + ll) * 4 + rg]
                    + accscr[(2 * 64 + ll) * 4 + rg] + accscr[(3 * 64 + ll) * 4 + rg];
            int row = ((ll >> 4) * 4) + rg;   // t_local  (C/D: row=(lane>>4)*4+reg)
            int col = ll & 15;                // u        (C/D: col=lane&15)
            partial[(size_t)(((fb * 32 + b) * 64 + tt * 16 + row) * 16) + col] = s;
        }
        __syncthreads();
    }
}

// ---------------- K3: sum partials + SimpleRNN (with adaptation) + FC ----------------
// grid = 8 blocks * 64 threads (1 wave): lanes = (bl 0..3, u 0..15), b = blk*4+bl.
__global__ __launch_bounds__(64) void k_rnn(const float* __restrict__ partial,
                                            const float* __restrict__ w_hh,
                                            const float* __restrict__ b_ih,
                                            const float* __restrict__ b_hh,
                                            const float* __restrict__ fc_w,
                                            const float* __restrict__ fc_b,
                                            float* __restrict__ out)
{
    __shared__ __align__(16) float preL[4096];   // [bl][t][u]
    __shared__ float hL[64];                     // [bl][u]
    const int l = threadIdx.x;
    const int bl = l >> 4, u = l & 15;
    const int b = blockIdx.x * 4 + bl;

    const float4* p4 = (const float4*)partial;   // 8192 float4 per fb slab
    float4* pl4 = (float4*)preL;
    for (int c = l; c < 1024; c += 64) {
        float4 s = {0.f, 0.f, 0.f, 0.f};
        for (int fb = 0; fb < 16; ++fb) {
            float4 v = p4[(size_t)fb * 8192 + blockIdx.x * 1024 + c];
            s.x += v.x; s.y += v.y; s.z += v.z; s.w += v.w;
        }
        pl4[c] = s;
    }

    float wv[16];
    #pragma unroll
    for (int mm = 0; mm < 4; ++mm) {
        float4 t4 = *(const float4*)(w_hh + u * 16 + mm * 4);
        wv[4*mm+0] = t4.x; wv[4*mm+1] = t4.y; wv[4*mm+2] = t4.z; wv[4*mm+3] = t4.w;
    }
    const float bsum = b_ih[u] + b_hh[u];
    float frow[16]; float fcb = 0.f;
    if (u < 2) {
        #pragma unroll
        for (int mm = 0; mm < 4; ++mm) {
            float4 t4 = *(const float4*)(fc_w + u * 16 + mm * 4);
            frow[4*mm+0] = t4.x; frow[4*mm+1] = t4.y; frow[4*mm+2] = t4.z; frow[4*mm+3] = t4.w;
        }
        fcb = fc_b[u];
    }
    hL[l] = 0.f;
    float ad = 0.f;
    __syncthreads();

    for (int t = 0; t < 64; ++t) {
        float hv[16];
        #pragma unroll
        for (int mm = 0; mm < 4; ++mm) {
            float4 h4 = *(const float4*)&hL[bl * 16 + mm * 4];
            hv[4*mm+0] = h4.x; hv[4*mm+1] = h4.y; hv[4*mm+2] = h4.z; hv[4*mm+3] = h4.w;
        }
        if (t > 0 && u < 2) {   // FC for t-1 from h_{t-1}
            float fcv = fcb;
            #pragma unroll
            for (int v2 = 0; v2 < 16; ++v2) fcv = fmaf(hv[v2], frow[v2], fcv);
            out[OFF_FC + (size_t)(b * 64 + (t - 1)) * 2 + u] = fcv;
        }
        float dot = 0.f;
        #pragma unroll
        for (int v2 = 0; v2 < 16; ++v2) dot = fmaf(hv[v2], wv[v2], dot);
        float v = preL[(bl * 64 + t) * 16 + u] + bsum + dot;
        float a = v - ad; a = a > 0.f ? a : 0.f;   // relu(pre - adapt); h = relu(a) = a
        ad = (ad + 0.4f * a) * 0.9f;
        out[OFF_RNN + (size_t)(b * 64 + t) * 16 + u] = a;
        __syncthreads();
        hL[l] = a;
        __syncthreads();
    }
    {   // FC for t = 63
        float hv[16];
        #pragma unroll
        for (int mm = 0; mm < 4; ++mm) {
            float4 h4 = *(const float4*)&hL[bl * 16 + mm * 4];
            hv[4*mm+0] = h4.x; hv[4*mm+1] = h4.y; hv[4*mm+2] = h4.z; hv[4*mm+3] = h4.w;
        }
        if (u < 2) {
            float fcv = fcb;
            #pragma unroll
            for (int v2 = 0; v2 < 16; ++v2) fcv = fmaf(hv[v2], frow[v2], fcv);
            out[OFF_FC + (size_t)(b * 64 + 63) * 2 + u] = fcv;
        }
    }
}

extern "C" void kernel_launch(void* const* d_in, const int* in_sizes, int n_in,
                              void* d_out, int out_size, void* d_ws, size_t ws_size,
                              hipStream_t stream)
{
    const float* x    = (const float*)d_in[0];
    const float* cw   = (const float*)d_in[1];
    const float* cb   = (const float*)d_in[2];
    const float* w_ih = (const float*)d_in[3];
    const float* w_hh = (const float*)d_in[4];
    const float* b_ih = (const float*)d_in[5];
    const float* b_hh = (const float*)d_in[6];
    const float* fc_w = (const float*)d_in[7];
    const float* fc_b = (const float*)d_in[8];
    float* out = (float*)d_out;
    float* partial = (float*)d_ws;   // 16 fb * 32 b * 64 t * 16 u fp32 = 2 MB

    k_conv<<<2048, 128, 0, stream>>>(x, cw, cb, out);
    k_adapt_proj<<<512, 256, 0, stream>>>(out + OFF_FLAT, w_ih, partial);
    k_rnn<<<8, 64, 0, stream>>>(partial, w_hh, b_ih, b_hh, fc_w, fc_b, out);
}